// Round 1
// baseline (329.275 us; speedup 1.0000x reference)
//
#include <hip/hip_runtime.h>
#include <hip/hip_bf16.h>
#include <string.h>

typedef __attribute__((ext_vector_type(8))) short short8;
typedef __attribute__((ext_vector_type(4))) float floatx4;

// Problem constants (fixed by setup_inputs)
// B=32, T=2048, D=512, U=512, M = B*T = 65536

__device__ inline uint packbf2(float lo, float hi) {
    __hip_bfloat162 h = __float22bfloat162_rn(make_float2(lo, hi));
    uint r; memcpy(&r, &h, 4); return r;
}

__device__ inline float tanh_fast(float x) {
    x = fminf(15.f, fmaxf(-15.f, x));
    float e = __expf(2.f * x);
    return __fdividef(e - 1.f, e + 1.f);
}

// ---- kernel 0a: pack W1_enc (512x512 fp32, row-major [k][n]) into bf16 MFMA
// B-fragment order: chunk (kk=k/32, ng=n/16) of 16n x 32k, lane-major so the
// GEMM's B load is global_load_dwordx4 at base + lane*16 (fully coalesced).
__global__ void kpack(const float* __restrict__ W1, ushort* __restrict__ Wp) {
    int idx = blockIdx.x * 256 + threadIdx.x;   // 0..262143
    int k = idx >> 9, n = idx & 511;
    float v = W1[idx];
    uint u; memcpy(&u, &v, 4);
    ushort b = (ushort)((u + 0x7FFF + ((u >> 16) & 1)) >> 16);  // RNE bf16
    int kk = k >> 5, ng = n >> 4;
    int lane = (n & 15) + ((k & 31) >> 3) * 16;
    Wp[(size_t)(kk * 32 + ng) * 512 + lane * 8 + (k & 7)] = b;
}

// ---- kernel 0b: dec[b][u] = sum_d h_dec[b][d] * W1[512+d][u] + b1[u]
__global__ void kdec(const float* __restrict__ W1, const float* __restrict__ hdec,
                     const float* __restrict__ b1, float* __restrict__ dec) {
    int b = blockIdx.x, u0 = threadIdx.x;
    float a0 = b1[u0], a1 = b1[u0 + 256];
    #pragma unroll 8
    for (int d = 0; d < 512; ++d) {
        float hv = hdec[b * 512 + d];
        const float* row = W1 + (size_t)(512 + d) * 512;
        a0 += hv * row[u0];
        a1 += hv * row[u0 + 256];
    }
    dec[b * 512 + u0] = a0;
    dec[b * 512 + u0 + 256] = a1;
}

// ---- kernel 1: fused GEMM + tanh + dot(W2) row-reduce -> e2 (pre-relu logit sums)
// Block tile 64 rows x 256 cols, 4 waves (each 64x64), K=512 in steps of 64.
// A: fp32 global -> cvt bf16 -> LDS (row pad +8); B: packed bf16 from L2.
__global__ __launch_bounds__(256) void kgemm(
        const float* __restrict__ A, const ushort* __restrict__ Wp,
        const float* __restrict__ dec, const float* __restrict__ W2,
        float* __restrict__ e2) {
    __shared__ __align__(16) ushort As[64][72];
    const int tid = threadIdx.x;
    const int lane = tid & 63, wave = tid >> 6;
    const int c = lane & 15, g = lane >> 4;
    const int rowbase = blockIdx.x * 64;
    const int bIdx = blockIdx.x >> 5;            // batch index (64 rows, 32 blocks/batch)
    const int nbase = blockIdx.y * 256 + wave * 64;

    floatx4 acc[4][4];
    #pragma unroll
    for (int i = 0; i < 4; i++)
        #pragma unroll
        for (int j = 0; j < 4; j++) acc[i][j] = (floatx4){0.f, 0.f, 0.f, 0.f};

    const int srow = tid >> 2;          // 0..63
    const int skc  = (tid & 3) * 16;    // 0,16,32,48

    for (int k0 = 0; k0 < 512; k0 += 64) {
        // load 16 fp32 of A per thread (coalesced), convert to bf16
        const float4* gp = (const float4*)(A + (size_t)(rowbase + srow) * 512 + k0 + skc);
        float4 f0 = gp[0], f1 = gp[1], f2 = gp[2], f3 = gp[3];
        uint4 u0, u1;
        u0.x = packbf2(f0.x, f0.y); u0.y = packbf2(f0.z, f0.w);
        u0.z = packbf2(f1.x, f1.y); u0.w = packbf2(f1.z, f1.w);
        u1.x = packbf2(f2.x, f2.y); u1.y = packbf2(f2.z, f2.w);
        u1.z = packbf2(f3.x, f3.y); u1.w = packbf2(f3.z, f3.w);
        __syncthreads();                 // previous iter's LDS reads complete
        *(uint4*)&As[srow][skc]     = u0;
        *(uint4*)&As[srow][skc + 8] = u1;
        __syncthreads();

        #pragma unroll
        for (int kk = 0; kk < 64; kk += 32) {
            const int kkidx = (k0 + kk) >> 5;
            short8 afr[4];
            #pragma unroll
            for (int i = 0; i < 4; i++)
                afr[i] = *(const short8*)&As[i * 16 + c][kk + g * 8];
            #pragma unroll
            for (int j = 0; j < 4; j++) {
                const int ng = (nbase >> 4) + j;
                short8 bfr = *(const short8*)&Wp[(size_t)(kkidx * 32 + ng) * 512 + lane * 8];
                #pragma unroll
                for (int i = 0; i < 4; i++)
                    acc[i][j] = __builtin_amdgcn_mfma_f32_16x16x32_bf16(afr[i], bfr, acc[i][j], 0, 0, 0);
            }
        }
    }

    // epilogue: z += dec; p = sum_u tanh(z)*W2[u] per row; reduce over 16 lanes
    float w2v[4], dv[4];
    #pragma unroll
    for (int j = 0; j < 4; j++) {
        int n = nbase + j * 16 + c;
        w2v[j] = W2[n];
        dv[j]  = dec[bIdx * 512 + n];
    }
    #pragma unroll
    for (int i = 0; i < 4; i++) {
        #pragma unroll
        for (int r = 0; r < 4; r++) {
            float p = 0.f;
            #pragma unroll
            for (int j = 0; j < 4; j++)
                p += tanh_fast(acc[i][j][r] + dv[j]) * w2v[j];
            p += __shfl_xor(p, 1, 16);
            p += __shfl_xor(p, 2, 16);
            p += __shfl_xor(p, 4, 16);
            p += __shfl_xor(p, 8, 16);
            if (c == 0)
                atomicAdd(&e2[rowbase + i * 16 + g * 4 + r], p);
        }
    }
}

// ---- kernel 2: per-batch relu(+b2) + softmax over T -> attn
__global__ void ksoftmax(const float* __restrict__ e2, const float* __restrict__ b2,
                         float* __restrict__ attn) {
    int b = blockIdx.x, tid = threadIdx.x;
    int lane = tid & 63, wave = tid >> 6;
    float b2v = b2[0];
    float f[8];
    float m = -1e30f;
    #pragma unroll
    for (int i = 0; i < 8; i++) {
        float z = e2[b * 2048 + i * 256 + tid] + b2v;
        f[i] = fmaxf(z, 0.f);
        m = fmaxf(m, f[i]);
    }
    #pragma unroll
    for (int off = 1; off < 64; off <<= 1) m = fmaxf(m, __shfl_xor(m, off));
    __shared__ float red[4], red2[4];
    if (lane == 0) red[wave] = m;
    __syncthreads();
    m = fmaxf(fmaxf(red[0], red[1]), fmaxf(red[2], red[3]));
    float s = 0.f;
    #pragma unroll
    for (int i = 0; i < 8; i++) { f[i] = __expf(f[i] - m); s += f[i]; }
    #pragma unroll
    for (int off = 1; off < 64; off <<= 1) s += __shfl_xor(s, off);
    if (lane == 0) red2[wave] = s;
    __syncthreads();
    s = red2[0] + red2[1] + red2[2] + red2[3];
    float inv = 1.f / s;
    #pragma unroll
    for (int i = 0; i < 8; i++)
        attn[b * 2048 + i * 256 + tid] = f[i] * inv;
}

// ---- kernel 3: context[b][d] = sum_t attn[b][t] * h_enc[b][t][d]
__global__ void kctx(const float* __restrict__ A, const float* __restrict__ attn,
                     float* __restrict__ ctx) {
    int b = blockIdx.x, ch = blockIdx.y, tid = threadIdx.x;
    int d0 = tid * 2;
    float ax = 0.f, ay = 0.f;
    const float* base = A + (size_t)b * 2048 * 512;
    #pragma unroll 8
    for (int tt = 0; tt < 128; ++tt) {
        int t = ch * 128 + tt;
        float a = attn[b * 2048 + t];
        float2 h = *(const float2*)(base + (size_t)t * 512 + d0);
        ax += a * h.x; ay += a * h.y;
    }
    atomicAdd(&ctx[b * 512 + d0],     ax);
    atomicAdd(&ctx[b * 512 + d0 + 1], ay);
}

extern "C" void kernel_launch(void* const* d_in, const int* in_sizes, int n_in,
                              void* d_out, int out_size, void* d_ws, size_t ws_size,
                              hipStream_t stream) {
    const float* h_enc = (const float*)d_in[0];
    const float* h_dec = (const float*)d_in[1];
    const float* W1    = (const float*)d_in[2];
    const float* b1    = (const float*)d_in[3];
    const float* W2    = (const float*)d_in[4];
    const float* b2    = (const float*)d_in[5];
    float* out  = (float*)d_out;
    float* ctx  = out;              // 32*512
    float* attn = out + 32 * 512;   // 32*2048

    char* ws = (char*)d_ws;
    ushort* Wp = (ushort*)ws;                                   // 512 KB
    float* dec = (float*)(ws + 512 * 512 * 2);                  // 64 KB
    float* e2  = (float*)(ws + 512 * 512 * 2 + 32 * 512 * 4);   // 256 KB

    hipMemsetAsync(e2, 0, 65536 * 4, stream);
    hipMemsetAsync(ctx, 0, 32 * 512 * 4, stream);

    kpack<<<1024, 256, 0, stream>>>(W1, Wp);
    kdec<<<32, 256, 0, stream>>>(W1, h_dec, b1, dec);
    dim3 g1(1024, 2);
    kgemm<<<g1, 256, 0, stream>>>(h_enc, Wp, dec, W2, e2);
    ksoftmax<<<32, 256, 0, stream>>>(e2, b2, attn);
    dim3 g3(32, 16);
    kctx<<<g3, 256, 0, stream>>>(h_enc, attn, ctx);
}

// Round 2
// 319.742 us; speedup vs baseline: 1.0298x; 1.0298x over previous
//
#include <hip/hip_runtime.h>
#include <hip/hip_bf16.h>
#include <string.h>

typedef __attribute__((ext_vector_type(8))) short short8;
typedef __attribute__((ext_vector_type(4))) float floatx4;

// B=32, T=2048, D=512, U=512, M = B*T = 65536

__device__ inline uint packbf2(float lo, float hi) {
    __hip_bfloat162 h = __float22bfloat162_rn(make_float2(lo, hi));
    uint r; memcpy(&r, &h, 4); return r;
}

__device__ inline float tanh_fast(float x) {
    x = fminf(15.f, fmaxf(-15.f, x));
    float e = __expf(2.f * x);
    return __fdividef(e - 1.f, e + 1.f);
}

// ---- kernel 0a: pack W1_enc (512x512 fp32 [k][n]) into bf16 MFMA B-fragment
// chunks: chunk (kc=k/32, ng=n/16) holds 512 bf16 lane-major: lane = (n&15) +
// ((k&31)>>3)*16, elem (k&7). GEMM B load = dwordx4 at chunk*1KB + lane*16.
__global__ void kpack(const float* __restrict__ W1, ushort* __restrict__ Wp) {
    int idx = blockIdx.x * 256 + threadIdx.x;   // 0..262143
    int k = idx >> 9, n = idx & 511;
    float v = W1[idx];
    uint u; memcpy(&u, &v, 4);
    ushort b = (ushort)((u + 0x7FFF + ((u >> 16) & 1)) >> 16);  // RNE bf16
    int kk = k >> 5, ng = n >> 4;
    int lane = (n & 15) + ((k & 31) >> 3) * 16;
    Wp[(size_t)(kk * 32 + ng) * 512 + lane * 8 + (k & 7)] = b;
}

// ---- kernel 0b: dec[b][u] = sum_d h_dec[b][d] * W1[512+d][u] + b1[u]
__global__ void kdec(const float* __restrict__ W1, const float* __restrict__ hdec,
                     const float* __restrict__ b1, float* __restrict__ dec) {
    int b = blockIdx.x, u0 = threadIdx.x;
    float a0 = b1[u0], a1 = b1[u0 + 256];
    #pragma unroll 8
    for (int d = 0; d < 512; ++d) {
        float hv = hdec[b * 512 + d];
        const float* row = W1 + (size_t)(512 + d) * 512;
        a0 += hv * row[u0];
        a1 += hv * row[u0 + 256];
    }
    dec[b * 512 + u0] = a0;
    dec[b * 512 + u0 + 256] = a1;
}

// ---- kernel 1: fused GEMM + tanh + dot(W2) -> e2 (pre-relu logits)
// Block: 256 thr = 4 waves; tile 64 rows x 512 cols (full U) x full K=512.
// A staged ONCE to LDS in A-fragment chunk order (fp32->bf16), one barrier,
// then a barrier-free K-loop of pure ds_read_b128 + global B frags + MFMA.
// Each wave: 64 rows x 128 cols (acc 4x8). e2 written directly (no atomics).
__global__ __launch_bounds__(256, 2) void kgemm(
        const float* __restrict__ A, const ushort* __restrict__ Wp,
        const float* __restrict__ dec, const float* __restrict__ W2,
        float* __restrict__ e2) {
    // A-fragment chunks: chunk (i=row16, kc=k32) at offset (i*16+kc)*512 ushorts
    __shared__ __align__(16) ushort As[32768];   // 64 KB
    __shared__ float red[4][64];                 // 1 KB
    const int tid = threadIdx.x;
    const int rowbase = blockIdx.x * 64;
    const int bIdx = blockIdx.x >> 5;            // 32 blocks per batch

    // ---- stage A tile: 64 rows x 512 k, fp32 -> bf16, fragment order
    #pragma unroll
    for (int p = 0; p < 16; ++p) {
        int s = tid + 256 * p;                   // 0..4095 lane-slots
        int chunk = s >> 6, l = s & 63;
        int i = chunk >> 4, kc = chunk & 15;
        int m = l & 15, gg = l >> 4;
        const float* gp = A + (size_t)(rowbase + i * 16 + m) * 512 + kc * 32 + gg * 8;
        float4 f0 = *(const float4*)gp;
        float4 f1 = *(const float4*)(gp + 4);
        uint4 u;
        u.x = packbf2(f0.x, f0.y); u.y = packbf2(f0.z, f0.w);
        u.z = packbf2(f1.x, f1.y); u.w = packbf2(f1.z, f1.w);
        *(uint4*)&As[chunk * 512 + l * 8] = u;
    }
    __syncthreads();

    const int lane = tid & 63, wave = tid >> 6;
    const int c = lane & 15, g = lane >> 4;

    floatx4 acc[4][8];
    #pragma unroll
    for (int i = 0; i < 4; i++)
        #pragma unroll
        for (int j = 0; j < 8; j++) acc[i][j] = (floatx4){0.f, 0.f, 0.f, 0.f};

    const int ng0 = wave * 8;                    // wave covers cols wave*128..+127
    #pragma unroll 2
    for (int kc = 0; kc < 16; ++kc) {
        short8 afr[4];
        #pragma unroll
        for (int i = 0; i < 4; ++i)
            afr[i] = *(const short8*)&As[(i * 16 + kc) * 512 + lane * 8];
        short8 bfr[8];
        #pragma unroll
        for (int j = 0; j < 8; ++j)
            bfr[j] = *(const short8*)&Wp[(size_t)(kc * 32 + ng0 + j) * 512 + lane * 8];
        #pragma unroll
        for (int j = 0; j < 8; ++j)
            #pragma unroll
            for (int i = 0; i < 4; ++i)
                acc[i][j] = __builtin_amdgcn_mfma_f32_16x16x32_bf16(afr[i], bfr[j], acc[i][j], 0, 0, 0);
    }

    // ---- epilogue: z += dec; p = sum_u tanh(z)*W2[u]; reduce 16 lanes + 4 waves
    float w2v[8], dv[8];
    #pragma unroll
    for (int j = 0; j < 8; j++) {
        int n = wave * 128 + j * 16 + c;
        w2v[j] = W2[n];
        dv[j]  = dec[bIdx * 512 + n];
    }
    #pragma unroll
    for (int i = 0; i < 4; i++) {
        #pragma unroll
        for (int r = 0; r < 4; r++) {
            float p = 0.f;
            #pragma unroll
            for (int j = 0; j < 8; j++)
                p += tanh_fast(acc[i][j][r] + dv[j]) * w2v[j];
            p += __shfl_xor(p, 1, 16);
            p += __shfl_xor(p, 2, 16);
            p += __shfl_xor(p, 4, 16);
            p += __shfl_xor(p, 8, 16);
            if (c == 0) red[wave][i * 16 + g * 4 + r] = p;
        }
    }
    __syncthreads();
    if (tid < 64)
        e2[rowbase + tid] = red[0][tid] + red[1][tid] + red[2][tid] + red[3][tid];
}

// ---- kernel 2: per-batch relu(+b2) + softmax over T -> attn
__global__ void ksoftmax(const float* __restrict__ e2, const float* __restrict__ b2,
                         float* __restrict__ attn) {
    int b = blockIdx.x, tid = threadIdx.x;
    int lane = tid & 63, wave = tid >> 6;
    float b2v = b2[0];
    float f[8];
    float m = -1e30f;
    #pragma unroll
    for (int i = 0; i < 8; i++) {
        float z = e2[b * 2048 + i * 256 + tid] + b2v;
        f[i] = fmaxf(z, 0.f);
        m = fmaxf(m, f[i]);
    }
    #pragma unroll
    for (int off = 1; off < 64; off <<= 1) m = fmaxf(m, __shfl_xor(m, off));
    __shared__ float red[4], red2[4];
    if (lane == 0) red[wave] = m;
    __syncthreads();
    m = fmaxf(fmaxf(red[0], red[1]), fmaxf(red[2], red[3]));
    float s = 0.f;
    #pragma unroll
    for (int i = 0; i < 8; i++) { f[i] = __expf(f[i] - m); s += f[i]; }
    #pragma unroll
    for (int off = 1; off < 64; off <<= 1) s += __shfl_xor(s, off);
    if (lane == 0) red2[wave] = s;
    __syncthreads();
    s = red2[0] + red2[1] + red2[2] + red2[3];
    float inv = 1.f / s;
    #pragma unroll
    for (int i = 0; i < 8; i++)
        attn[b * 2048 + i * 256 + tid] = f[i] * inv;
}

// ---- kernel 3: context[b][d] = sum_t attn[b][t] * h_enc[b][t][d]
// grid (32 b, 8 chunks of 256 t); float4 loads; attn staged in LDS;
// LDS-reduce the two t-halves, then one atomic set per (block, d4).
__global__ void kctx(const float* __restrict__ A, const float* __restrict__ attn,
                     float* __restrict__ ctx) {
    __shared__ float at[256];
    __shared__ float4 red[128];
    int b = blockIdx.x, ch = blockIdx.y, tid = threadIdx.x;
    at[tid] = attn[b * 2048 + ch * 256 + tid];
    __syncthreads();
    int dt = tid & 127, th = tid >> 7;
    const float* base = A + (size_t)b * 2048 * 512 + (size_t)(ch * 256 + th * 128) * 512 + dt * 4;
    const float* aw = at + th * 128;
    float4 acc = (float4){0.f, 0.f, 0.f, 0.f};
    #pragma unroll 8
    for (int tt = 0; tt < 128; ++tt) {
        float a = aw[tt];
        float4 h = *(const float4*)(base + (size_t)tt * 512);
        acc.x += a * h.x; acc.y += a * h.y; acc.z += a * h.z; acc.w += a * h.w;
    }
    if (th == 1) red[dt] = acc;
    __syncthreads();
    if (th == 0) {
        float4 o = red[dt];
        float* cp = ctx + b * 512 + dt * 4;
        atomicAdd(cp + 0, acc.x + o.x);
        atomicAdd(cp + 1, acc.y + o.y);
        atomicAdd(cp + 2, acc.z + o.z);
        atomicAdd(cp + 3, acc.w + o.w);
    }
}

extern "C" void kernel_launch(void* const* d_in, const int* in_sizes, int n_in,
                              void* d_out, int out_size, void* d_ws, size_t ws_size,
                              hipStream_t stream) {
    const float* h_enc = (const float*)d_in[0];
    const float* h_dec = (const float*)d_in[1];
    const float* W1    = (const float*)d_in[2];
    const float* b1    = (const float*)d_in[3];
    const float* W2    = (const float*)d_in[4];
    const float* b2    = (const float*)d_in[5];
    float* out  = (float*)d_out;
    float* ctx  = out;              // 32*512
    float* attn = out + 32 * 512;   // 32*2048

    char* ws = (char*)d_ws;
    ushort* Wp = (ushort*)ws;                                   // 512 KB
    float* dec = (float*)(ws + 512 * 512 * 2);                  // 64 KB
    float* e2  = (float*)(ws + 512 * 512 * 2 + 32 * 512 * 4);   // 256 KB

    hipMemsetAsync(ctx, 0, 32 * 512 * 4, stream);

    kpack<<<1024, 256, 0, stream>>>(W1, Wp);
    kdec<<<32, 256, 0, stream>>>(W1, h_dec, b1, dec);
    kgemm<<<1024, 256, 0, stream>>>(h_enc, Wp, dec, W2, e2);
    ksoftmax<<<32, 256, 0, stream>>>(e2, b2, attn);
    dim3 g3(32, 8);
    kctx<<<g3, 256, 0, stream>>>(h_enc, attn, ctx);
}

// Round 3
// 272.350 us; speedup vs baseline: 1.2090x; 1.1740x over previous
//
#include <hip/hip_runtime.h>
#include <hip/hip_bf16.h>
#include <string.h>

typedef __attribute__((ext_vector_type(8))) short short8;
typedef __attribute__((ext_vector_type(4))) float floatx4;

// B=32, T=2048, D=512, U=512, M = B*T = 65536

__device__ inline uint packbf2(float lo, float hi) {
    __hip_bfloat162 h = __float22bfloat162_rn(make_float2(lo, hi));
    uint r; memcpy(&r, &h, 4); return r;
}

__device__ inline float tanh_fast(float x) {
    x = fminf(15.f, fmaxf(-15.f, x));
    float e = __expf(2.f * x);
    return __fdividef(e - 1.f, e + 1.f);
}

// ---- kernel 0a: pack W1_enc (512x512 fp32 [k][n]) -> bf16 MFMA B-frag chunks.
// One wave per chunk (kc,ng): lane l = (n&15) + ((k&31)>>3)*16 holds 8 k-elems.
// Output store = dwordx4 at chunk*1KB + lane*16 (fully coalesced).
__global__ void kpack(const float* __restrict__ W1, ushort* __restrict__ Wp) {
    int wid = blockIdx.x * 4 + (threadIdx.x >> 6);   // 0..511 chunks
    int l = threadIdx.x & 63;
    int kc = wid >> 5, ng = wid & 31;
    int m = l & 15, g = l >> 4;
    const float* src = W1 + (size_t)(kc * 32 + g * 8) * 512 + ng * 16 + m;
    uint u4[4];
    #pragma unroll
    for (int e = 0; e < 4; ++e)
        u4[e] = packbf2(src[(size_t)(2 * e) * 512], src[(size_t)(2 * e + 1) * 512]);
    *(uint4*)(Wp + (size_t)wid * 512 + l * 8) = *(uint4*)u4;
}

// ---- kernel 0b: dec[b][u] = sum_d h_dec[b][d]*W1[512+d][u] + b1[u]
// grid 256: block (b = blk>>3, u-chunk = blk&7); 4 d-quarters reduced in LDS.
__global__ void kdec(const float* __restrict__ W1, const float* __restrict__ hdec,
                     const float* __restrict__ b1, float* __restrict__ dec) {
    __shared__ float red[4][64];
    int b = blockIdx.x >> 3, ug = blockIdx.x & 7;
    int tid = threadIdx.x;
    int u = ug * 64 + (tid & 63), dq = tid >> 6;
    const float* hb = hdec + b * 512 + dq * 128;
    const float* w = W1 + (size_t)(512 + dq * 128) * 512 + u;
    float a = 0.f;
    #pragma unroll 8
    for (int d = 0; d < 128; ++d)
        a += hb[d] * w[(size_t)d * 512];
    red[dq][tid & 63] = a;
    __syncthreads();
    if (tid < 64)
        dec[b * 512 + ug * 64 + tid] =
            red[0][tid] + red[1][tid] + red[2][tid] + red[3][tid] + b1[ug * 64 + tid];
}

// ---- kernel 1: fused GEMM + tanh + dot(W2) -> e2 (pre-relu logits)
// 512 thr = 8 waves; block tile 64 rows x 512 cols (full U) x K=512.
// Wave tile 64x64 (acc 4x4 = 64 VGPR) -> launch_bounds(512,4) = 4 waves/SIMD.
// A staged once to LDS in A-frag order; barrier-free K-loop; no atomics.
__global__ __launch_bounds__(512, 4) void kgemm(
        const float* __restrict__ A, const ushort* __restrict__ Wp,
        const float* __restrict__ dec, const float* __restrict__ W2,
        float* __restrict__ e2) {
    __shared__ __align__(16) ushort As[32768];   // 64 KB
    __shared__ float red[8][64];                 // 2 KB
    const int tid = threadIdx.x;
    const int rowbase = blockIdx.x * 64;
    const int bIdx = blockIdx.x >> 5;            // 32 blocks per batch

    // stage A tile: 64 rows x 512 k, fp32 -> bf16, fragment-chunk order
    #pragma unroll
    for (int p = 0; p < 8; ++p) {
        int s = tid + 512 * p;                   // 0..4095 lane-slots
        int chunk = s >> 6, l = s & 63;
        int i = chunk >> 4, kc = chunk & 15;
        int m = l & 15, gg = l >> 4;
        const float* gp = A + (size_t)(rowbase + i * 16 + m) * 512 + kc * 32 + gg * 8;
        float4 f0 = *(const float4*)gp;
        float4 f1 = *(const float4*)(gp + 4);
        uint4 u;
        u.x = packbf2(f0.x, f0.y); u.y = packbf2(f0.z, f0.w);
        u.z = packbf2(f1.x, f1.y); u.w = packbf2(f1.z, f1.w);
        *(uint4*)&As[chunk * 512 + l * 8] = u;
    }
    __syncthreads();

    const int lane = tid & 63, wave = tid >> 6;
    const int c = lane & 15, g = lane >> 4;

    floatx4 acc[4][4];
    #pragma unroll
    for (int i = 0; i < 4; i++)
        #pragma unroll
        for (int j = 0; j < 4; j++) acc[i][j] = (floatx4){0.f, 0.f, 0.f, 0.f};

    const int ng0 = wave * 4;                    // wave covers cols wave*64..+63
    #pragma unroll 2
    for (int kc = 0; kc < 16; ++kc) {
        short8 bfr[4];
        #pragma unroll
        for (int j = 0; j < 4; ++j)
            bfr[j] = *(const short8*)&Wp[(size_t)(kc * 32 + ng0 + j) * 512 + lane * 8];
        short8 afr[4];
        #pragma unroll
        for (int i = 0; i < 4; ++i)
            afr[i] = *(const short8*)&As[(i * 16 + kc) * 512 + lane * 8];
        #pragma unroll
        for (int j = 0; j < 4; ++j)
            #pragma unroll
            for (int i = 0; i < 4; ++i)
                acc[i][j] = __builtin_amdgcn_mfma_f32_16x16x32_bf16(afr[i], bfr[j], acc[i][j], 0, 0, 0);
    }

    // epilogue: z += dec; p = sum_u tanh(z)*W2[u]; reduce 16 lanes + 8 waves
    float w2v[4], dv[4];
    #pragma unroll
    for (int j = 0; j < 4; j++) {
        int n = wave * 64 + j * 16 + c;
        w2v[j] = W2[n];
        dv[j]  = dec[bIdx * 512 + n];
    }
    #pragma unroll
    for (int i = 0; i < 4; i++) {
        #pragma unroll
        for (int r = 0; r < 4; r++) {
            float p = 0.f;
            #pragma unroll
            for (int j = 0; j < 4; j++)
                p += tanh_fast(acc[i][j][r] + dv[j]) * w2v[j];
            p += __shfl_xor(p, 1, 16);
            p += __shfl_xor(p, 2, 16);
            p += __shfl_xor(p, 4, 16);
            p += __shfl_xor(p, 8, 16);
            if (c == 0) red[wave][i * 16 + g * 4 + r] = p;
        }
    }
    __syncthreads();
    if (tid < 64) {
        float s = 0.f;
        #pragma unroll
        for (int w = 0; w < 8; ++w) s += red[w][tid];
        e2[rowbase + tid] = s;
    }
}

// ---- kernel 2: per-batch relu(+b2) + softmax over T -> attn
__global__ void ksoftmax(const float* __restrict__ e2, const float* __restrict__ b2,
                         float* __restrict__ attn) {
    int b = blockIdx.x, tid = threadIdx.x;
    int lane = tid & 63, wave = tid >> 6;
    float b2v = b2[0];
    float f[8];
    float m = -1e30f;
    #pragma unroll
    for (int i = 0; i < 8; i++) {
        float z = e2[b * 2048 + i * 256 + tid] + b2v;
        f[i] = fmaxf(z, 0.f);
        m = fmaxf(m, f[i]);
    }
    #pragma unroll
    for (int off = 1; off < 64; off <<= 1) m = fmaxf(m, __shfl_xor(m, off));
    __shared__ float red[4], red2[4];
    if (lane == 0) red[wave] = m;
    __syncthreads();
    m = fmaxf(fmaxf(red[0], red[1]), fmaxf(red[2], red[3]));
    float s = 0.f;
    #pragma unroll
    for (int i = 0; i < 8; i++) { f[i] = __expf(f[i] - m); s += f[i]; }
    #pragma unroll
    for (int off = 1; off < 64; off <<= 1) s += __shfl_xor(s, off);
    if (lane == 0) red2[wave] = s;
    __syncthreads();
    s = red2[0] + red2[1] + red2[2] + red2[3];
    float inv = 1.f / s;
    #pragma unroll
    for (int i = 0; i < 8; i++)
        attn[b * 2048 + i * 256 + tid] = f[i] * inv;
}

// ---- kernel 3: partial context: part[b][ch][d] = sum_{t in chunk} attn*h_enc
// grid (32, 32): 64-t chunks, 4 blocks/CU, deterministic (no atomics).
__global__ void kctx(const float* __restrict__ A, const float* __restrict__ attn,
                     float* __restrict__ part) {
    __shared__ float at[64];
    __shared__ float4 red[128];
    int b = blockIdx.x, ch = blockIdx.y, tid = threadIdx.x;
    if (tid < 64) at[tid] = attn[b * 2048 + ch * 64 + tid];
    __syncthreads();
    int dt = tid & 127, th = tid >> 7;
    const float* base = A + ((size_t)b * 2048 + ch * 64 + th * 32) * 512 + dt * 4;
    const float* aw = at + th * 32;
    float4 acc = (float4){0.f, 0.f, 0.f, 0.f};
    #pragma unroll 8
    for (int tt = 0; tt < 32; ++tt) {
        float a = aw[tt];
        float4 h = *(const float4*)(base + (size_t)tt * 512);
        acc.x += a * h.x; acc.y += a * h.y; acc.z += a * h.z; acc.w += a * h.w;
    }
    if (th == 1) red[dt] = acc;
    __syncthreads();
    if (th == 0) {
        float4 o = red[dt];
        float4 r; r.x = acc.x + o.x; r.y = acc.y + o.y;
        r.z = acc.z + o.z; r.w = acc.w + o.w;
        *(float4*)(part + ((size_t)b * 32 + ch) * 512 + dt * 4) = r;
    }
}

// ---- kernel 4: ctx[b][d] = sum_ch part[b][ch][d]
__global__ void kfin(const float* __restrict__ part, float* __restrict__ ctx) {
    int idx = blockIdx.x * 256 + threadIdx.x;   // 0..16383
    int b = idx >> 9, d = idx & 511;
    const float* p = part + (size_t)b * 32 * 512 + d;
    float s = 0.f;
    #pragma unroll
    for (int cI = 0; cI < 32; ++cI) s += p[cI * 512];
    ctx[idx] = s;
}

extern "C" void kernel_launch(void* const* d_in, const int* in_sizes, int n_in,
                              void* d_out, int out_size, void* d_ws, size_t ws_size,
                              hipStream_t stream) {
    const float* h_enc = (const float*)d_in[0];
    const float* h_dec = (const float*)d_in[1];
    const float* W1    = (const float*)d_in[2];
    const float* b1    = (const float*)d_in[3];
    const float* W2    = (const float*)d_in[4];
    const float* b2    = (const float*)d_in[5];
    float* out  = (float*)d_out;
    float* ctx  = out;              // 32*512
    float* attn = out + 32 * 512;   // 32*2048

    char* ws = (char*)d_ws;
    ushort* Wp = (ushort*)ws;                                    // 512 KB
    float* dec  = (float*)(ws + (512 * 512 * 2));                // 64 KB
    float* e2   = (float*)(ws + (512 * 512 * 2) + (32 * 512 * 4));              // 256 KB
    float* part = (float*)(ws + (512 * 512 * 2) + (32 * 512 * 4) + (65536 * 4)); // 2 MB

    kpack<<<128, 256, 0, stream>>>(W1, Wp);
    kdec<<<256, 256, 0, stream>>>(W1, h_dec, b1, dec);
    kgemm<<<1024, 512, 0, stream>>>(h_enc, Wp, dec, W2, e2);
    ksoftmax<<<32, 256, 0, stream>>>(e2, b2, attn);
    dim3 g3(32, 32);
    kctx<<<g3, 256, 0, stream>>>(h_enc, attn, part);
    kfin<<<64, 256, 0, stream>>>(part, ctx);
}